// Round 1
// baseline (78.723 us; speedup 1.0000x reference)
//
#include <hip/hip_runtime.h>
#include <math.h>

// Tropical max/min-plus pseudo-matmul.
// out[b,u] = max_f(x[b,f] + w[f,u])  for u < 128
//          = min_f(x[b,f] + w[f,u])  for u >= 128
// min via sign trick: min(x+w) = -max(-x + -w); sign applied in LDS staging
// and on the final store (exact in fp32 => matches reference bitwise).

#define BATCH  2048
#define FEAT   512
#define UNITS  256
#define MSPLIT 128

#define BM 32
#define BN 32
#define BK 64
// xs rows read as b128 along k by 4 rows/wave: stride 68 words -> banks 4r+k, conflict-free.
#define XS_STRIDE 68
// ws rows read as b64 along c (c=2*tx): stride 36 words -> banks 4k+2tx, 32 distinct, conflict-free.
#define WS_STRIDE 36

__global__ __launch_bounds__(256, 2) void tropical_mm_kernel(
    const float* __restrict__ x, const float* __restrict__ w, float* __restrict__ out)
{
    __shared__ float xs[BM][XS_STRIDE];  // [row][k]
    __shared__ float ws[BK][WS_STRIDE];  // [k][col]

    const int tid   = threadIdx.x;          // 0..255
    const int tx    = tid & 15;             // unit dim, 0..15
    const int ty    = tid >> 4;             // batch dim, 0..15
    const int ubase = blockIdx.x * BN;
    const int bbase = blockIdx.y * BM;
    const float sgn = (ubase < MSPLIT) ? 1.0f : -1.0f;

    // staging thread mapping
    const int xrow = tid >> 4;              // 0..15 (two passes: +0, +16)
    const int xc4  = (tid & 15) << 2;       // 0..60
    const int wrow = tid >> 3;              // 0..31 (two passes: +0, +32)
    const int wc4  = (tid & 7) << 2;        // 0..28

    const int r0 = ty * 2;
    const int r1 = r0 + 1;
    const int c0 = tx * 2;

    float acc00 = -INFINITY, acc01 = -INFINITY;
    float acc10 = -INFINITY, acc11 = -INFINITY;

    for (int k0 = 0; k0 < FEAT; k0 += BK) {
        // ---- stage x tile (32 x 64), coalesced float4, sign-folded ----
        {
            const float4 v0 = *(const float4*)&x[(size_t)(bbase + xrow)      * FEAT + k0 + xc4];
            const float4 v1 = *(const float4*)&x[(size_t)(bbase + xrow + 16) * FEAT + k0 + xc4];
            *(float4*)&xs[xrow]
                [xc4]      = make_float4(sgn*v0.x, sgn*v0.y, sgn*v0.z, sgn*v0.w);
            *(float4*)&xs[xrow + 16][xc4] = make_float4(sgn*v1.x, sgn*v1.y, sgn*v1.z, sgn*v1.w);
        }
        // ---- stage w tile (64 x 32), coalesced float4, sign-folded ----
        {
            const float4 v0 = *(const float4*)&w[(size_t)(k0 + wrow)      * UNITS + ubase + wc4];
            const float4 v1 = *(const float4*)&w[(size_t)(k0 + wrow + 32) * UNITS + ubase + wc4];
            *(float4*)&ws[wrow]     [wc4] = make_float4(sgn*v0.x, sgn*v0.y, sgn*v0.z, sgn*v0.w);
            *(float4*)&ws[wrow + 32][wc4] = make_float4(sgn*v1.x, sgn*v1.y, sgn*v1.z, sgn*v1.w);
        }
        __syncthreads();

        // ---- compute: 2x2 per thread, k-unroll 4 ----
        #pragma unroll
        for (int kk = 0; kk < BK; kk += 4) {
            const float4 a0 = *(const float4*)&xs[r0][kk];   // row r0, k..k+3
            const float4 a1 = *(const float4*)&xs[r1][kk];   // row r1, k..k+3
            const float2 b0 = *(const float2*)&ws[kk + 0][c0];
            const float2 b1 = *(const float2*)&ws[kk + 1][c0];
            const float2 b2 = *(const float2*)&ws[kk + 2][c0];
            const float2 b3 = *(const float2*)&ws[kk + 3][c0];

            acc00 = fmaxf(fmaxf(acc00, a0.x + b0.x), a0.y + b1.x);
            acc00 = fmaxf(fmaxf(acc00, a0.z + b2.x), a0.w + b3.x);
            acc01 = fmaxf(fmaxf(acc01, a0.x + b0.y), a0.y + b1.y);
            acc01 = fmaxf(fmaxf(acc01, a0.z + b2.y), a0.w + b3.y);
            acc10 = fmaxf(fmaxf(acc10, a1.x + b0.x), a1.y + b1.x);
            acc10 = fmaxf(fmaxf(acc10, a1.z + b2.x), a1.w + b3.x);
            acc11 = fmaxf(fmaxf(acc11, a1.x + b0.y), a1.y + b1.y);
            acc11 = fmaxf(fmaxf(acc11, a1.z + b2.y), a1.w + b3.y);
        }
        __syncthreads();
    }

    // ---- epilogue: undo sign, coalesced float2 stores ----
    const size_t obase = (size_t)(bbase + r0) * UNITS + ubase + c0;
    *(float2*)&out[obase]         = make_float2(sgn * acc00, sgn * acc01);
    *(float2*)&out[obase + UNITS] = make_float2(sgn * acc10, sgn * acc11);
}

extern "C" void kernel_launch(void* const* d_in, const int* in_sizes, int n_in,
                              void* d_out, int out_size, void* d_ws, size_t ws_size,
                              hipStream_t stream) {
    const float* x = (const float*)d_in[0];   // (2048, 512)
    const float* w = (const float*)d_in[1];   // (512, 256)
    float* out = (float*)d_out;               // (2048, 256)

    dim3 grid(UNITS / BN, BATCH / BM);        // (8, 64) = 512 blocks
    dim3 block(256);
    tropical_mm_kernel<<<grid, block, 0, stream>>>(x, w, out);
}